// Round 1
// baseline (23523.550 us; speedup 1.0000x reference)
//
#include <hip/hip_runtime.h>
#include <hip/hip_bf16.h>

// Problem constants
constexpr int Bn = 256, Tn = 200, Dn = 32, Hn = 512, PHn = 256, PREPn = 16;
constexpr int COVn = 32, COVHn = 128, CLFHn = 64;
constexpr float DTc = 0.05f;

// Packed bf16 weight segment offsets (in bf16 elements) inside d_ws.
// Layout per matrix [N outputs, K inputs]: elem (k,j) at ((k>>2)*N + j)*4 + (k&3)
constexpr int OFF_WHR   = 0;
constexpr int OFF_WHZ   = 262144;
constexpr int OFF_WHH   = 524288;
constexpr int OFF_WP1   = 786432;
constexpr int OFF_WP2   = 917504;
constexpr int OFF_WIH   = 933888;
constexpr int OFF_WHH2  = 1720320;
constexpr int OFF_WCLF1 = 2506752;
constexpr int WS_ELEMS  = 2539520;

struct PrepArgs {
  const float* src[8];
  __hip_bfloat16* dst;
};

__global__ void prep_pack_kernel(PrepArgs a) {
  int idx = blockIdx.x * 256 + threadIdx.x;
  if (idx >= WS_ELEMS) return;
  int s, off, N, K;
  if      (idx < 262144)  { s = 0; off = 0;       N = 512;  K = 512; }
  else if (idx < 524288)  { s = 1; off = 262144;  N = 512;  K = 512; }
  else if (idx < 786432)  { s = 2; off = 524288;  N = 512;  K = 512; }
  else if (idx < 917504)  { s = 3; off = 786432;  N = 256;  K = 512; }
  else if (idx < 933888)  { s = 4; off = 917504;  N = 64;   K = 256; }
  else if (idx < 1720320) { s = 5; off = 933888;  N = 1536; K = 512; }
  else if (idx < 2506752) { s = 6; off = 1720320; N = 1536; K = 512; }
  else                    { s = 7; off = 2506752; N = 64;   K = 512; }
  const int li = idx - off;
  const int r  = li & 3;
  const int t2 = li >> 2;
  const int j  = t2 % N;
  const int k4 = t2 / N;
  a.dst[idx] = __float2bfloat16(a.src[s][(size_t)j * K + (k4 * 4 + r)]);
}

struct MainArgs {
  const float *cov, *X, *M;
  const float *Wc1, *bc1, *Wc2, *bc2;
  const float *Whr, *Whz, *Whh;
  const float *Wp1, *bp1, *Wp2, *bp2;
  const float *w_prep, *bias_prep;
  const float *W_ih, *W_hh, *b_ih, *b_hh;
  const float *Wclf1, *bclf1, *Wclf2, *bclf2;
  const __hip_bfloat16* WP;
  float* out;
};

__device__ __forceinline__ float bf_lo(unsigned u) { return __uint_as_float(u << 16); }
__device__ __forceinline__ float bf_hi(unsigned u) { return __uint_as_float(u & 0xffff0000u); }
__device__ __forceinline__ float sigmoidf(float x) { return 1.0f / (1.0f + __expf(-x)); }
__device__ __forceinline__ float dot4(float4 a, float4 b) {
  return a.x * b.x + a.y * b.y + a.z * b.z + a.w * b.w;
}

template<bool PACKED>
__device__ __forceinline__ float4 ldw4(const __hip_bfloat16* WP, const float* W,
                                       int N, int K, int k4, int j) {
  if constexpr (PACKED) {
    const uint2 w = *reinterpret_cast<const uint2*>(WP + (size_t)(k4 * N + j) * 4);
    float4 r;
    r.x = bf_lo(w.x); r.y = bf_hi(w.x);
    r.z = bf_lo(w.y); r.w = bf_hi(w.y);
    return r;
  } else {
    return *reinterpret_cast<const float4*>(W + (size_t)j * K + k4 * 4);
  }
}

template<bool PACKED>
__global__ __launch_bounds__(512)
void gruode_kernel(MainArgs a) {
  const int b   = blockIdx.x;
  const int tid = threadIdx.x;

  __shared__ __align__(16) float h_s[Hn];
  __shared__ __align__(16) float rh_s[Hn];
  __shared__ __align__(16) float z_s[Hn];
  __shared__ __align__(16) float gi_s[Hn];
  __shared__ __align__(16) float q_s[PHn];
  __shared__ __align__(16) float p_s[2 * Dn];
  __shared__ __align__(16) float t1_s[COVHn];
  __shared__ float xrow_s[Dn], mrow_s[Dn];
  __shared__ float covrow_s[COVn];
  __shared__ float obs_s;

  const __hip_bfloat16* WhrP   = a.WP + OFF_WHR;
  const __hip_bfloat16* WhzP   = a.WP + OFF_WHZ;
  const __hip_bfloat16* WhhP   = a.WP + OFF_WHH;
  const __hip_bfloat16* Wp1P   = a.WP + OFF_WP1;
  const __hip_bfloat16* Wp2P   = a.WP + OFF_WP2;
  const __hip_bfloat16* WihP   = a.WP + OFF_WIH;
  const __hip_bfloat16* Whh2P  = a.WP + OFF_WHH2;
  const __hip_bfloat16* Wclf1P = a.WP + OFF_WCLF1;

  // ---- h0 = tanh(relu(cov@Wc1^T + bc1)@Wc2^T + bc2), fp32 ----
  if (tid < COVn) covrow_s[tid] = a.cov[b * COVn + tid];
  __syncthreads();
  if (tid < COVHn) {
    float acc = a.bc1[tid];
    #pragma unroll
    for (int k = 0; k < COVn; ++k) acc += covrow_s[k] * a.Wc1[tid * COVn + k];
    t1_s[tid] = fmaxf(acc, 0.0f);
  }
  __syncthreads();
  {
    float acc = a.bc2[tid];
    for (int k = 0; k < COVHn; ++k) acc += t1_s[k] * a.Wc2[tid * COVHn + k];
    h_s[tid] = tanhf(acc);
  }
  __syncthreads();

  for (int t = 0; t < Tn; ++t) {
    // ---- A: r = sig(h@Whr^T), z = sig(h@Whz^T); rh = r*h ----
    {
      float ar = 0.0f, az = 0.0f;
      for (int k4 = 0; k4 < Hn / 4; ++k4) {
        const float4 hv = *reinterpret_cast<const float4*>(&h_s[k4 * 4]);
        const float4 wr = ldw4<PACKED>(WhrP, a.Whr, Hn, Hn, k4, tid);
        const float4 wz = ldw4<PACKED>(WhzP, a.Whz, Hn, Hn, k4, tid);
        ar += dot4(hv, wr);
        az += dot4(hv, wz);
      }
      rh_s[tid] = sigmoidf(ar) * h_s[tid];
      z_s[tid]  = sigmoidf(az);
    }
    __syncthreads();

    // ---- B: u = tanh(rh@Whh^T); Euler step h += DT*(1-z)*(u-h) ----
    {
      float au = 0.0f;
      for (int k4 = 0; k4 < Hn / 4; ++k4) {
        const float4 hv = *reinterpret_cast<const float4*>(&rh_s[k4 * 4]);
        const float4 wu = ldw4<PACKED>(WhhP, a.Whh, Hn, Hn, k4, tid);
        au += dot4(hv, wu);
      }
      const float u  = tanhf(au);
      const float hj = h_s[tid];
      const float hn = hj + DTc * (1.0f - z_s[tid]) * (u - hj);
      __syncthreads();             // all reads of h_s in this phase done
      h_s[tid] = hn;
    }
    __syncthreads();

    // ---- C: q = relu(h@Wp1^T + bp1); side-load X,M rows ----
    if (tid < PHn) {
      float acc = a.bp1[tid];
      for (int k4 = 0; k4 < Hn / 4; ++k4) {
        const float4 hv = *reinterpret_cast<const float4*>(&h_s[k4 * 4]);
        const float4 w  = ldw4<PACKED>(Wp1P, a.Wp1, PHn, Hn, k4, tid);
        acc += dot4(hv, w);
      }
      q_s[tid] = fmaxf(acc, 0.0f);
    } else if (tid >= 448 && tid < 480) {
      const int d = tid - 448;
      mrow_s[d] = a.M[((size_t)t * Bn + b) * Dn + d];
    } else if (tid >= 480) {
      const int d = tid - 480;
      xrow_s[d] = a.X[((size_t)t * Bn + b) * Dn + d];
    }
    __syncthreads();

    // ---- D: p = q@Wp2^T + bp2 ----
    if (tid < 2 * Dn) {
      float acc = a.bp2[tid];
      for (int k4 = 0; k4 < PHn / 4; ++k4) {
        const float4 qv = *reinterpret_cast<const float4*>(&q_s[k4 * 4]);
        const float4 w  = ldw4<PACKED>(Wp2P, a.Wp2, 2 * Dn, PHn, k4, tid);
        acc += dot4(qv, w);
      }
      p_s[tid] = acc;
    }
    __syncthreads();

    // ---- E: prep einsum -> gi, obs flag ----
    {
      const int d = tid >> 4, pp = tid & 15;
      const float xv   = xrow_s[d];
      const float mean = p_s[d];
      const float logv = p_s[Dn + d];
      const float err  = (xv - mean) * __expf(-0.5f * logv);
      float acc = a.bias_prep[d * PREPn + pp];
      acc += xv   * a.w_prep[(d * 4 + 0) * PREPn + pp];
      acc += mean * a.w_prep[(d * 4 + 1) * PREPn + pp];
      acc += logv * a.w_prep[(d * 4 + 2) * PREPn + pp];
      acc += err  * a.w_prep[(d * 4 + 3) * PREPn + pp];
      gi_s[tid] = fmaxf(acc, 0.0f) * mrow_s[d];
      if (tid == 0) {
        float s = 0.0f;
        for (int dd = 0; dd < Dn; ++dd) s += mrow_s[dd];
        obs_s = (s > 0.0f) ? 1.0f : 0.0f;
      }
    }
    __syncthreads();

    // ---- F: GRUCell gates (torch order r,z,n), obs-masked update ----
    {
      float axr = a.b_ih[tid], axz = a.b_ih[Hn + tid], axn = a.b_ih[2 * Hn + tid];
      float ahr = a.b_hh[tid], ahz = a.b_hh[Hn + tid], ahn = a.b_hh[2 * Hn + tid];
      for (int k4 = 0; k4 < Hn / 4; ++k4) {
        const float4 gv = *reinterpret_cast<const float4*>(&gi_s[k4 * 4]);
        const float4 hv = *reinterpret_cast<const float4*>(&h_s[k4 * 4]);
        const float4 w0 = ldw4<PACKED>(WihP, a.W_ih, 3 * Hn, Hn, k4, tid);
        const float4 w1 = ldw4<PACKED>(WihP, a.W_ih, 3 * Hn, Hn, k4, Hn + tid);
        const float4 w2 = ldw4<PACKED>(WihP, a.W_ih, 3 * Hn, Hn, k4, 2 * Hn + tid);
        axr += dot4(gv, w0); axz += dot4(gv, w1); axn += dot4(gv, w2);
        const float4 v0 = ldw4<PACKED>(Whh2P, a.W_hh, 3 * Hn, Hn, k4, tid);
        const float4 v1 = ldw4<PACKED>(Whh2P, a.W_hh, 3 * Hn, Hn, k4, Hn + tid);
        const float4 v2 = ldw4<PACKED>(Whh2P, a.W_hh, 3 * Hn, Hn, k4, 2 * Hn + tid);
        ahr += dot4(hv, v0); ahz += dot4(hv, v1); ahn += dot4(hv, v2);
      }
      const float rg   = sigmoidf(axr + ahr);
      const float zg   = sigmoidf(axz + ahz);
      const float ng   = tanhf(axn + rg * ahn);
      const float hcur = h_s[tid];
      const float hnew = (1.0f - zg) * ng + zg * hcur;
      const float hout = (obs_s > 0.0f) ? hnew : hcur;
      __syncthreads();             // all reads of h_s/gi_s in this phase done
      h_s[tid] = hout;
    }
    __syncthreads();

    // ---- G: classifier pred = relu(h@Wclf1^T+b)@Wclf2^T + b ----
    if (tid < CLFHn) {
      float acc = a.bclf1[tid];
      for (int k4 = 0; k4 < Hn / 4; ++k4) {
        const float4 hv = *reinterpret_cast<const float4*>(&h_s[k4 * 4]);
        const float4 w  = ldw4<PACKED>(Wclf1P, a.Wclf1, CLFHn, Hn, k4, tid);
        acc += dot4(hv, w);
      }
      float c = fmaxf(acc, 0.0f) * a.Wclf2[tid];
      #pragma unroll
      for (int off = 32; off > 0; off >>= 1) c += __shfl_down(c, off, 64);
      if (tid == 0) a.out[t * Bn + b] = c + a.bclf2[0];
    }
    // no sync needed: next write to h_s is in phase B, behind phase A's barrier
  }
}

extern "C" void kernel_launch(void* const* d_in, const int* in_sizes, int n_in,
                              void* d_out, int out_size, void* d_ws, size_t ws_size,
                              hipStream_t stream) {
  MainArgs a;
  a.cov  = (const float*)d_in[0];
  a.X    = (const float*)d_in[1];
  a.M    = (const float*)d_in[2];
  a.Wc1  = (const float*)d_in[3];  a.bc1 = (const float*)d_in[4];
  a.Wc2  = (const float*)d_in[5];  a.bc2 = (const float*)d_in[6];
  a.Whr  = (const float*)d_in[7];  a.Whz = (const float*)d_in[8];  a.Whh = (const float*)d_in[9];
  a.Wp1  = (const float*)d_in[10]; a.bp1 = (const float*)d_in[11];
  a.Wp2  = (const float*)d_in[12]; a.bp2 = (const float*)d_in[13];
  a.w_prep = (const float*)d_in[14]; a.bias_prep = (const float*)d_in[15];
  a.W_ih = (const float*)d_in[16]; a.W_hh = (const float*)d_in[17];
  a.b_ih = (const float*)d_in[18]; a.b_hh = (const float*)d_in[19];
  a.Wclf1 = (const float*)d_in[20]; a.bclf1 = (const float*)d_in[21];
  a.Wclf2 = (const float*)d_in[22]; a.bclf2 = (const float*)d_in[23];
  a.WP  = (const __hip_bfloat16*)d_ws;
  a.out = (float*)d_out;

  const bool packed = ws_size >= (size_t)WS_ELEMS * sizeof(__hip_bfloat16);
  if (packed) {
    PrepArgs p;
    p.src[0] = a.Whr;  p.src[1] = a.Whz;  p.src[2] = a.Whh;  p.src[3] = a.Wp1;
    p.src[4] = a.Wp2;  p.src[5] = a.W_ih; p.src[6] = a.W_hh; p.src[7] = a.Wclf1;
    p.dst = (__hip_bfloat16*)d_ws;
    prep_pack_kernel<<<(WS_ELEMS + 255) / 256, 256, 0, stream>>>(p);
    gruode_kernel<true><<<Bn, Hn, 0, stream>>>(a);
  } else {
    gruode_kernel<false><<<Bn, Hn, 0, stream>>>(a);
  }
}